// Round 11
// baseline (277.488 us; speedup 1.0000x reference)
//
#include <hip/hip_runtime.h>
#include <hip/hip_bf16.h>

// QuantiZ: e = codebook[4096,1024] @ proj_w[256,1024]^T + proj_b
//          zidx[t] = argmin_k ||z_t - e_k||, quant[t] = e[zidx[t]]
// d_out FLOAT32: [ zidx as float (32768) | quant (32768*256) ].
// Score GEMM: exact split-bf16 (hi+lo), 4 terms, v_mfma_f32_16x16x32_bf16.
// R11: B global prefetch depth-2 (covers ~225cy L2 latency with ~310cy of
//      MFMA), A ds_read depth-1, static-index pipeline arrays under full
//      unroll; split_e fused into proj_gemm epilogue.

#define K_CODES 4096
#define CDIM    256
#define IDIM    1024
#define NTOK    32768

typedef __attribute__((ext_vector_type(8))) short short8;
typedef __attribute__((ext_vector_type(4))) float f32x4;

__device__ __forceinline__ unsigned short f32_to_bf16_rne(float f) {
  union { float f; unsigned int u; } x; x.f = f;
  unsigned int r = x.u + 0x7FFFu + ((x.u >> 16) & 1u);
  return (unsigned short)(r >> 16);
}
__device__ __forceinline__ float bf16_to_f32(unsigned short h) {
  union { unsigned int u; float f; } x; x.u = ((unsigned int)h) << 16;
  return x.f;
}

// ---- Kernel A: e = cb @ pw^T + pb (f32 64x64 tile) + fused Ect split -------
// Ect layout: frag(kb 0..15, ct 0..255) = 1024 B at (kb*256+ct)*1024,
// lane lf = g*16 + cl holds k-octet g of code ct*16+cl; kb0-7 hi, 8-15 lo.
extern "C" __global__ __launch_bounds__(256)
void proj_gemm(const float* __restrict__ cb, const float* __restrict__ pw,
               const float* __restrict__ pb, float* __restrict__ e,
               unsigned short* __restrict__ Ect) {
  __shared__ float As[64][33];
  __shared__ float Bs[64][33];
  const int tid = threadIdx.x;
  const int tx = tid & 15, ty = tid >> 4;
  const int m0 = blockIdx.y << 6;
  const int n0 = blockIdx.x << 6;
  const int r  = tid >> 2;
  const int c8 = (tid & 3) << 3;
  float acc[4][4] = {};
  for (int k0 = 0; k0 < IDIM; k0 += 32) {
    float4 a0 = *(const float4*)&cb[(m0 + r) * IDIM + k0 + c8];
    float4 a1 = *(const float4*)&cb[(m0 + r) * IDIM + k0 + c8 + 4];
    float4 b0 = *(const float4*)&pw[(n0 + r) * IDIM + k0 + c8];
    float4 b1 = *(const float4*)&pw[(n0 + r) * IDIM + k0 + c8 + 4];
    __syncthreads();
    As[r][c8+0]=a0.x; As[r][c8+1]=a0.y; As[r][c8+2]=a0.z; As[r][c8+3]=a0.w;
    As[r][c8+4]=a1.x; As[r][c8+5]=a1.y; As[r][c8+6]=a1.z; As[r][c8+7]=a1.w;
    Bs[r][c8+0]=b0.x; Bs[r][c8+1]=b0.y; Bs[r][c8+2]=b0.z; Bs[r][c8+3]=b0.w;
    Bs[r][c8+4]=b1.x; Bs[r][c8+5]=b1.y; Bs[r][c8+6]=b1.z; Bs[r][c8+7]=b1.w;
    __syncthreads();
    #pragma unroll
    for (int kk = 0; kk < 32; ++kk) {
      float av[4], bv[4];
      #pragma unroll
      for (int i = 0; i < 4; ++i) av[i] = As[ty*4 + i][kk];
      #pragma unroll
      for (int j = 0; j < 4; ++j) bv[j] = Bs[tx*4 + j][kk];
      #pragma unroll
      for (int i = 0; i < 4; ++i)
        #pragma unroll
        for (int j = 0; j < 4; ++j)
          acc[i][j] += av[i] * bv[j];
    }
  }
  // epilogue: write e (f32) and fragment-linear hi/lo bf16 Ect
  const int col0 = n0 + tx*4;
  const int kb   = col0 >> 5;
  const int g    = (col0 >> 3) & 3;
  const int half = (col0 >> 2) & 1;
  #pragma unroll
  for (int i = 0; i < 4; ++i) {
    const int row = m0 + ty*4 + i;
    float vv[4];
    unsigned short h4[4], l4[4];
    #pragma unroll
    for (int j = 0; j < 4; ++j) {
      vv[j] = acc[i][j] + pb[col0 + j];
      h4[j] = f32_to_bf16_rne(vv[j]);
      l4[j] = f32_to_bf16_rne(vv[j] - bf16_to_f32(h4[j]));
    }
    *(float4*)&e[(size_t)row * CDIM + col0] = *(float4*)vv;
    const int ct = row >> 4, cl = row & 15;
    const size_t fi = ((size_t)(kb      * 256 + ct) * 64 + g*16 + cl) * 8 + half*4;
    const size_t fo = ((size_t)((kb+8)  * 256 + ct) * 64 + g*16 + cl) * 8 + half*4;
    *(ushort4*)&Ect[fi] = *(ushort4*)h4;
    *(ushort4*)&Ect[fo] = *(ushort4*)l4;
  }
}

// ---------------- Kernel A3: e2[k] = sum_c e[k][c]^2 ------------------------
extern "C" __global__ __launch_bounds__(256)
void compute_e2(const float* __restrict__ e, float* __restrict__ e2) {
  const int gid  = blockIdx.x * 256 + threadIdx.x;
  const int w    = gid >> 6;
  const int lane = threadIdx.x & 63;
  float4 v = *(const float4*)&e[(size_t)w * CDIM + (lane << 2)];
  float s = v.x*v.x + v.y*v.y + v.z*v.z + v.w*v.w;
  #pragma unroll
  for (int off = 32; off > 0; off >>= 1) s += __shfl_down(s, off, 64);
  if (lane == 0) e2[w] = s;
}

// ---------------- Kernel B: MFMA score + argmin (barrier-free loop) ---------
// 64 tokens/block, 8 waves; wave = 64 tok x 32 codes (i in 4, jj in 2).
// LDS: Z as 64 fragment-linear frags: frag(i 0..3, kb 0..15) = 1 KB at
//      (i*16+kb)*1024; lane l reads base + l*16 -> zero bank conflicts.
// Pipeline: B global prefetch depth-2, A ds_read depth-1, static arrays.
extern "C" __global__ __launch_bounds__(512, 2)
void score_mfma(const float* __restrict__ z, const unsigned short* __restrict__ Ect,
                const float* __restrict__ e2g, int* __restrict__ zidx_i,
                float* __restrict__ zidx_f) {
  extern __shared__ __align__(16) char smem[];   // 64 KB Z + 4 KB reduce
  char* Zb = smem;

  const int tid = threadIdx.x;
  const int l   = tid & 63;
  const int w   = tid >> 6;          // wave 0..7: code slice w*32 within each cc
  const int t0  = blockIdx.x << 6;   // 64 tokens per block

  // ---- stage Z (hi/lo bf16) into fragment-linear LDS frags ----
  {
    const int r  = tid >> 3;              // token row 0..63
    const int cq = tid & 7;               // col base cq*32
    const int i4 = r >> 4;                // frag i
    const int rl = (r & 15) << 4;         // lane-slot byte within frag
    #pragma unroll
    for (int it = 0; it < 4; ++it) {
      const int col = cq*32 + it*8;       // g = it, kb_hi = cq, kb_lo = cq+8
      const float4 v0 = *(const float4*)&z[(size_t)(t0 + r) * CDIM + col];
      const float4 v1 = *(const float4*)&z[(size_t)(t0 + r) * CDIM + col + 4];
      float vv[8] = {v0.x,v0.y,v0.z,v0.w,v1.x,v1.y,v1.z,v1.w};
      unsigned int hp[4], lp[4];
      #pragma unroll
      for (int c = 0; c < 4; ++c) {
        unsigned short h0 = f32_to_bf16_rne(vv[2*c]);
        unsigned short h1 = f32_to_bf16_rne(vv[2*c+1]);
        unsigned short l0 = f32_to_bf16_rne(vv[2*c]   - bf16_to_f32(h0));
        unsigned short l1 = f32_to_bf16_rne(vv[2*c+1] - bf16_to_f32(h1));
        hp[c] = (unsigned int)h0 | ((unsigned int)h1 << 16);
        lp[c] = (unsigned int)l0 | ((unsigned int)l1 << 16);
      }
      const int lane_b = it*256 + rl;     // (g*16 + (r&15)) * 16
      *(uint4*)(Zb + (size_t)(i4*16 + cq    ) * 1024 + lane_b) = *(uint4*)hp;
      *(uint4*)(Zb + (size_t)(i4*16 + cq + 8) * 1024 + lane_b) = *(uint4*)lp;
    }
  }
  __syncthreads();   // Z ready; no further barriers until final reduce

  float bestv[4][4];
  int   besti[4][4];
  #pragma unroll
  for (int i = 0; i < 4; ++i)
    #pragma unroll
    for (int r = 0; r < 4; ++r) { bestv[i][r] = 3.4e38f; besti[i][r] = 0; }

  const int cl = l & 15;
  const int g  = l >> 4;

  // per-lane E base: frag(kb, ct) byte offset = kb*262144 + ct*1024 + l*16
  const char* ebase = (const char*)Ect + (size_t)l * 16 + (size_t)w * 2048;
  const char* Zl    = Zb + (size_t)l * 16;

  // pipeline carries across cc iterations
  short8 cAH[4], cAL[4];               // A(kw=0)
  short8 cBH0[2], cBL0[2], cBH1[2], cBL1[2];  // B(kw=0), B(kw=1)

  // prologue
  #pragma unroll
  for (int i = 0; i < 4; ++i) {
    cAH[i] = *(const short8*)(Zl + (size_t)(i*16 + 0) * 1024);
    cAL[i] = *(const short8*)(Zl + (size_t)(i*16 + 8) * 1024);
  }
  #pragma unroll
  for (int jj = 0; jj < 2; ++jj) {
    cBH0[jj] = *(const short8*)(ebase + (size_t)0 * 262144 + jj * 1024);
    cBL0[jj] = *(const short8*)(ebase + (size_t)8 * 262144 + jj * 1024);
    cBH1[jj] = *(const short8*)(ebase + (size_t)1 * 262144 + jj * 1024);
    cBL1[jj] = *(const short8*)(ebase + (size_t)9 * 262144 + jj * 1024);
  }

  for (int cc = 0; cc < 16; ++cc) {              // 256-code chunks
    const char* ecc  = ebase + (size_t)cc * 16384;
    const char* eccn = ebase + (size_t)((cc + 1) & 15) * 16384;

    short8 AH[9][4], AL[9][4];   // A(kw) slots, 8 = next-cc kw0
    short8 BH[10][2], BL[10][2]; // B(kw) slots, 8/9 = next-cc kw0/kw1
    #pragma unroll
    for (int i = 0; i < 4; ++i) { AH[0][i] = cAH[i]; AL[0][i] = cAL[i]; }
    #pragma unroll
    for (int jj = 0; jj < 2; ++jj) {
      BH[0][jj] = cBH0[jj]; BL[0][jj] = cBL0[jj];
      BH[1][jj] = cBH1[jj]; BL[1][jj] = cBL1[jj];
    }

    f32x4 acc[4][2];
    #pragma unroll
    for (int i = 0; i < 4; ++i)
      #pragma unroll
      for (int jj = 0; jj < 2; ++jj) acc[i][jj] = (f32x4){0.f,0.f,0.f,0.f};

    float e2v[2];
    #pragma unroll
    for (int jj = 0; jj < 2; ++jj)
      e2v[jj] = e2g[cc*256 + w*32 + jj*16 + cl];

    #pragma unroll
    for (int kw = 0; kw < 8; ++kw) {
      // issue B(kw+2): depth-2 prefetch (cross into next cc at kw>=6)
      {
        const char* src = (kw < 6) ? ecc : eccn;
        const int kwb = (kw < 6) ? (kw + 2) : (kw - 6);
        #pragma unroll
        for (int jj = 0; jj < 2; ++jj) {
          BH[kw+2][jj] = *(const short8*)(src + (size_t)(kwb    ) * 262144 + jj * 1024);
          BL[kw+2][jj] = *(const short8*)(src + (size_t)(kwb + 8) * 262144 + jj * 1024);
        }
      }
      // issue A(kw+1): depth-1 (kw=7 -> next cc's kw0, same Z frags)
      {
        const int kwa = (kw + 1) & 7;
        #pragma unroll
        for (int i = 0; i < 4; ++i) {
          AH[kw+1][i] = *(const short8*)(Zl + (size_t)(i*16 + kwa    ) * 1024);
          AL[kw+1][i] = *(const short8*)(Zl + (size_t)(i*16 + kwa + 8) * 1024);
        }
      }
      __builtin_amdgcn_s_setprio(1);
      #pragma unroll
      for (int i = 0; i < 4; ++i)
        #pragma unroll
        for (int jj = 0; jj < 2; ++jj)
          acc[i][jj] = __builtin_amdgcn_mfma_f32_16x16x32_bf16(AH[kw][i], BH[kw][jj], acc[i][jj], 0, 0, 0);
      #pragma unroll
      for (int i = 0; i < 4; ++i)
        #pragma unroll
        for (int jj = 0; jj < 2; ++jj)
          acc[i][jj] = __builtin_amdgcn_mfma_f32_16x16x32_bf16(AH[kw][i], BL[kw][jj], acc[i][jj], 0, 0, 0);
      #pragma unroll
      for (int i = 0; i < 4; ++i)
        #pragma unroll
        for (int jj = 0; jj < 2; ++jj)
          acc[i][jj] = __builtin_amdgcn_mfma_f32_16x16x32_bf16(AL[kw][i], BH[kw][jj], acc[i][jj], 0, 0, 0);
      #pragma unroll
      for (int i = 0; i < 4; ++i)
        #pragma unroll
        for (int jj = 0; jj < 2; ++jj)
          acc[i][jj] = __builtin_amdgcn_mfma_f32_16x16x32_bf16(AL[kw][i], BL[kw][jj], acc[i][jj], 0, 0, 0);
      __builtin_amdgcn_s_setprio(0);
    }
    // carry pipeline regs to next cc
    #pragma unroll
    for (int i = 0; i < 4; ++i) { cAH[i] = AH[8][i]; cAL[i] = AL[8][i]; }
    #pragma unroll
    for (int jj = 0; jj < 2; ++jj) {
      cBH0[jj] = BH[8][jj]; cBL0[jj] = BL[8][jj];
      cBH1[jj] = BH[9][jj]; cBL1[jj] = BL[9][jj];
    }
    // epilogue: scores -> running argmin (codes ascend: cc outer, jj inner)
    #pragma unroll
    for (int jj = 0; jj < 2; ++jj) {
      const int code = cc*256 + w*32 + jj*16 + cl;
      #pragma unroll
      for (int i = 0; i < 4; ++i)
        #pragma unroll
        for (int r = 0; r < 4; ++r) {
          const float sc = e2v[jj] - 2.0f * acc[i][jj][r];
          if (sc < bestv[i][r]) { bestv[i][r] = sc; besti[i][r] = code; }
        }
    }
  }

  // ---- final argmin reduce: 16 code-lanes, then 8 waves via LDS ----
  struct RP { float v; int i; };
  RP* red = (RP*)(smem + 65536);     // [64][8]
  #pragma unroll
  for (int i = 0; i < 4; ++i)
    #pragma unroll
    for (int r = 0; r < 4; ++r) {
      float v = bestv[i][r]; int bi = besti[i][r];
      #pragma unroll
      for (int m = 1; m < 16; m <<= 1) {
        const float ov = __shfl_xor(v, m, 64);
        const int   oi = __shfl_xor(bi, m, 64);
        if (ov < v || (ov == v && oi < bi)) { v = ov; bi = oi; }
      }
      if (cl == 0) {                 // lanes 0,16,32,48 own token i*16+g*4+r
        const int tl = i*16 + g*4 + r;
        red[tl*8 + w].v = v; red[tl*8 + w].i = bi;
      }
    }
  __syncthreads();
  if (tid < 64) {
    float v = red[tid*8].v; int bi = red[tid*8].i;
    #pragma unroll
    for (int x = 1; x < 8; ++x) {
      const float ov = red[tid*8 + x].v; const int oi = red[tid*8 + x].i;
      if (ov < v || (ov == v && oi < bi)) { v = ov; bi = oi; }
    }
    zidx_i[t0 + tid] = bi;
    zidx_f[t0 + tid] = (float)bi;
  }
}

// ---------------- Kernel C: quant = e[zidx]  (f32 out) ----------------------
extern "C" __global__ __launch_bounds__(256)
void gather_quant(const float* __restrict__ e, const int* __restrict__ zidx,
                  float* __restrict__ q) {
  const int gid = blockIdx.x * 256 + threadIdx.x;
  const int t = gid >> 6;
  const int c = (gid & 63) << 2;
  const int idx = zidx[t];
  const float4 v = *(const float4*)&e[(size_t)idx * CDIM + c];
  *(float4*)&q[(size_t)t * CDIM + c] = v;
}

// ---------------- launch ----------------------------------------------------
extern "C" void kernel_launch(void* const* d_in, const int* in_sizes, int n_in,
                              void* d_out, int out_size, void* d_ws, size_t ws_size,
                              hipStream_t stream) {
  const float* encode = (const float*)d_in[0];
  const float* cb     = (const float*)d_in[1];
  const float* pw     = (const float*)d_in[2];
  const float* pb     = (const float*)d_in[3];

  float* e  = (float*)d_ws;                           // 4 MB
  float* e2 = e + (size_t)K_CODES * CDIM;             // 16 KB
  int*   zi = (int*)(e2 + K_CODES);                   // 128 KB
  unsigned short* Ect = (unsigned short*)(zi + NTOK); // 4 MB fragment-linear

  float* out     = (float*)d_out;
  float* zidx_f  = out;
  float* quant_f = out + NTOK;

  (void)hipFuncSetAttribute((const void*)score_mfma,
                            hipFuncAttributeMaxDynamicSharedMemorySize, 69632);

  proj_gemm<<<dim3(CDIM/64, K_CODES/64), 256, 0, stream>>>(cb, pw, pb, e, Ect);
  compute_e2<<<(K_CODES*64)/256, 256, 0, stream>>>(e, e2);
  score_mfma<<<NTOK/64, 512, 69632, stream>>>(encode, Ect, e2, zi, zidx_f);
  gather_quant<<<(NTOK*64)/256, 256, 0, stream>>>(e, zi, quant_f);
}

// Round 12
// 256.815 us; speedup vs baseline: 1.0805x; 1.0805x over previous
//
#include <hip/hip_runtime.h>
#include <hip/hip_bf16.h>

// QuantiZ: e = codebook[4096,1024] @ proj_w[256,1024]^T + proj_b
//          zidx[t] = argmin_k ||z_t - e_k||, quant[t] = e[zidx[t]]
// d_out FLOAT32: [ zidx as float (32768) | quant (32768*256) ].
// Score GEMM: split-bf16 3-term (hi*hi + hi*lo + lo*hi; lo*lo ~ 6e-5 abs,
// dropped), v_mfma_f32_16x16x32_bf16.
// R12: 24 MFMA/kw (-25% MFMA floor), gather fused into score_mfma tail.

#define K_CODES 4096
#define CDIM    256
#define IDIM    1024
#define NTOK    32768

typedef __attribute__((ext_vector_type(8))) short short8;
typedef __attribute__((ext_vector_type(4))) float f32x4;

__device__ __forceinline__ unsigned short f32_to_bf16_rne(float f) {
  union { float f; unsigned int u; } x; x.f = f;
  unsigned int r = x.u + 0x7FFFu + ((x.u >> 16) & 1u);
  return (unsigned short)(r >> 16);
}
__device__ __forceinline__ float bf16_to_f32(unsigned short h) {
  union { unsigned int u; float f; } x; x.u = ((unsigned int)h) << 16;
  return x.f;
}

// ---- Kernel A: e = cb @ pw^T + pb (f32 64x64 tile) + fused Ect split -------
// Ect layout: frag(kb 0..15, ct 0..255) = 1024 B at (kb*256+ct)*1024,
// lane lf = g*16 + cl holds k-octet g of code ct*16+cl; kb0-7 hi, 8-15 lo.
extern "C" __global__ __launch_bounds__(256)
void proj_gemm(const float* __restrict__ cb, const float* __restrict__ pw,
               const float* __restrict__ pb, float* __restrict__ e,
               unsigned short* __restrict__ Ect) {
  __shared__ float As[64][33];
  __shared__ float Bs[64][33];
  const int tid = threadIdx.x;
  const int tx = tid & 15, ty = tid >> 4;
  const int m0 = blockIdx.y << 6;
  const int n0 = blockIdx.x << 6;
  const int r  = tid >> 2;
  const int c8 = (tid & 3) << 3;
  float acc[4][4] = {};
  for (int k0 = 0; k0 < IDIM; k0 += 32) {
    float4 a0 = *(const float4*)&cb[(m0 + r) * IDIM + k0 + c8];
    float4 a1 = *(const float4*)&cb[(m0 + r) * IDIM + k0 + c8 + 4];
    float4 b0 = *(const float4*)&pw[(n0 + r) * IDIM + k0 + c8];
    float4 b1 = *(const float4*)&pw[(n0 + r) * IDIM + k0 + c8 + 4];
    __syncthreads();
    As[r][c8+0]=a0.x; As[r][c8+1]=a0.y; As[r][c8+2]=a0.z; As[r][c8+3]=a0.w;
    As[r][c8+4]=a1.x; As[r][c8+5]=a1.y; As[r][c8+6]=a1.z; As[r][c8+7]=a1.w;
    Bs[r][c8+0]=b0.x; Bs[r][c8+1]=b0.y; Bs[r][c8+2]=b0.z; Bs[r][c8+3]=b0.w;
    Bs[r][c8+4]=b1.x; Bs[r][c8+5]=b1.y; Bs[r][c8+6]=b1.z; Bs[r][c8+7]=b1.w;
    __syncthreads();
    #pragma unroll
    for (int kk = 0; kk < 32; ++kk) {
      float av[4], bv[4];
      #pragma unroll
      for (int i = 0; i < 4; ++i) av[i] = As[ty*4 + i][kk];
      #pragma unroll
      for (int j = 0; j < 4; ++j) bv[j] = Bs[tx*4 + j][kk];
      #pragma unroll
      for (int i = 0; i < 4; ++i)
        #pragma unroll
        for (int j = 0; j < 4; ++j)
          acc[i][j] += av[i] * bv[j];
    }
  }
  // epilogue: write e (f32) and fragment-linear hi/lo bf16 Ect
  const int col0 = n0 + tx*4;
  const int kb   = col0 >> 5;
  const int g    = (col0 >> 3) & 3;
  const int half = (col0 >> 2) & 1;
  #pragma unroll
  for (int i = 0; i < 4; ++i) {
    const int row = m0 + ty*4 + i;
    float vv[4];
    unsigned short h4[4], l4[4];
    #pragma unroll
    for (int j = 0; j < 4; ++j) {
      vv[j] = acc[i][j] + pb[col0 + j];
      h4[j] = f32_to_bf16_rne(vv[j]);
      l4[j] = f32_to_bf16_rne(vv[j] - bf16_to_f32(h4[j]));
    }
    *(float4*)&e[(size_t)row * CDIM + col0] = *(float4*)vv;
    const int ct = row >> 4, cl = row & 15;
    const size_t fi = ((size_t)(kb      * 256 + ct) * 64 + g*16 + cl) * 8 + half*4;
    const size_t fo = ((size_t)((kb+8)  * 256 + ct) * 64 + g*16 + cl) * 8 + half*4;
    *(ushort4*)&Ect[fi] = *(ushort4*)h4;
    *(ushort4*)&Ect[fo] = *(ushort4*)l4;
  }
}

// ---------------- Kernel A3: e2[k] = sum_c e[k][c]^2 ------------------------
extern "C" __global__ __launch_bounds__(256)
void compute_e2(const float* __restrict__ e, float* __restrict__ e2) {
  const int gid  = blockIdx.x * 256 + threadIdx.x;
  const int w    = gid >> 6;
  const int lane = threadIdx.x & 63;
  float4 v = *(const float4*)&e[(size_t)w * CDIM + (lane << 2)];
  float s = v.x*v.x + v.y*v.y + v.z*v.z + v.w*v.w;
  #pragma unroll
  for (int off = 32; off > 0; off >>= 1) s += __shfl_down(s, off, 64);
  if (lane == 0) e2[w] = s;
}

// ---------------- Kernel B: MFMA score + argmin + fused gather --------------
// 64 tokens/block, 8 waves; wave = 64 tok x 32 codes (i in 4, jj in 2).
// LDS: Z as 64 fragment-linear frags (zero-conflict lane-order ds_read).
// 3-term split: hi*hi + hi*lo + lo*hi (24 MFMA per kw).
extern "C" __global__ __launch_bounds__(512, 2)
void score_mfma(const float* __restrict__ z, const unsigned short* __restrict__ Ect,
                const float* __restrict__ e2g, const float* __restrict__ eg,
                float* __restrict__ zidx_f, float* __restrict__ quant) {
  extern __shared__ __align__(16) char smem[];   // 64K Z + 4K red + 256 idx
  char* Zb = smem;

  const int tid = threadIdx.x;
  const int l   = tid & 63;
  const int w   = tid >> 6;          // wave 0..7: code slice w*32 within each cc
  const int t0  = blockIdx.x << 6;   // 64 tokens per block

  // ---- stage Z (hi/lo bf16) into fragment-linear LDS frags ----
  {
    const int r  = tid >> 3;              // token row 0..63
    const int cq = tid & 7;               // col base cq*32
    const int i4 = r >> 4;                // frag i
    const int rl = (r & 15) << 4;         // lane-slot byte within frag
    #pragma unroll
    for (int it = 0; it < 4; ++it) {
      const int col = cq*32 + it*8;       // g = it, kb_hi = cq, kb_lo = cq+8
      const float4 v0 = *(const float4*)&z[(size_t)(t0 + r) * CDIM + col];
      const float4 v1 = *(const float4*)&z[(size_t)(t0 + r) * CDIM + col + 4];
      float vv[8] = {v0.x,v0.y,v0.z,v0.w,v1.x,v1.y,v1.z,v1.w};
      unsigned int hp[4], lp[4];
      #pragma unroll
      for (int c = 0; c < 4; ++c) {
        unsigned short h0 = f32_to_bf16_rne(vv[2*c]);
        unsigned short h1 = f32_to_bf16_rne(vv[2*c+1]);
        unsigned short l0 = f32_to_bf16_rne(vv[2*c]   - bf16_to_f32(h0));
        unsigned short l1 = f32_to_bf16_rne(vv[2*c+1] - bf16_to_f32(h1));
        hp[c] = (unsigned int)h0 | ((unsigned int)h1 << 16);
        lp[c] = (unsigned int)l0 | ((unsigned int)l1 << 16);
      }
      const int lane_b = it*256 + rl;     // (g*16 + (r&15)) * 16
      *(uint4*)(Zb + (size_t)(i4*16 + cq    ) * 1024 + lane_b) = *(uint4*)hp;
      *(uint4*)(Zb + (size_t)(i4*16 + cq + 8) * 1024 + lane_b) = *(uint4*)lp;
    }
  }
  __syncthreads();   // Z ready; no further barriers until final reduce

  float bestv[4][4];
  int   besti[4][4];
  #pragma unroll
  for (int i = 0; i < 4; ++i)
    #pragma unroll
    for (int r = 0; r < 4; ++r) { bestv[i][r] = 3.4e38f; besti[i][r] = 0; }

  const int cl = l & 15;
  const int g  = l >> 4;

  // per-lane E base: frag(kb, ct) byte offset = kb*262144 + ct*1024 + l*16
  const char* ebase = (const char*)Ect + (size_t)l * 16 + (size_t)w * 2048;
  const char* Zl    = Zb + (size_t)l * 16;

  for (int cc = 0; cc < 16; ++cc) {              // 256-code chunks
    const char* ecc = ebase + (size_t)cc * 16384;

    f32x4 acc[4][2];
    #pragma unroll
    for (int i = 0; i < 4; ++i)
      #pragma unroll
      for (int jj = 0; jj < 2; ++jj) acc[i][jj] = (f32x4){0.f,0.f,0.f,0.f};

    float e2v[2];
    #pragma unroll
    for (int jj = 0; jj < 2; ++jj)
      e2v[jj] = e2g[cc*256 + w*32 + jj*16 + cl];

    #pragma unroll
    for (int kw = 0; kw < 8; ++kw) {
      short8 aH[4], aL[4], bH[2], bL[2];
      #pragma unroll
      for (int jj = 0; jj < 2; ++jj) {
        bH[jj] = *(const short8*)(ecc + (size_t)(kw    ) * 262144 + jj * 1024);
        bL[jj] = *(const short8*)(ecc + (size_t)(kw + 8) * 262144 + jj * 1024);
      }
      #pragma unroll
      for (int i = 0; i < 4; ++i) {
        aH[i] = *(const short8*)(Zl + (size_t)(i*16 + kw    ) * 1024);
        aL[i] = *(const short8*)(Zl + (size_t)(i*16 + kw + 8) * 1024);
      }
      __builtin_amdgcn_s_setprio(1);
      #pragma unroll
      for (int i = 0; i < 4; ++i)
        #pragma unroll
        for (int jj = 0; jj < 2; ++jj)
          acc[i][jj] = __builtin_amdgcn_mfma_f32_16x16x32_bf16(aH[i], bH[jj], acc[i][jj], 0, 0, 0);
      #pragma unroll
      for (int i = 0; i < 4; ++i)
        #pragma unroll
        for (int jj = 0; jj < 2; ++jj)
          acc[i][jj] = __builtin_amdgcn_mfma_f32_16x16x32_bf16(aH[i], bL[jj], acc[i][jj], 0, 0, 0);
      #pragma unroll
      for (int i = 0; i < 4; ++i)
        #pragma unroll
        for (int jj = 0; jj < 2; ++jj)
          acc[i][jj] = __builtin_amdgcn_mfma_f32_16x16x32_bf16(aL[i], bH[jj], acc[i][jj], 0, 0, 0);
      __builtin_amdgcn_s_setprio(0);
    }
    // epilogue: scores -> running argmin (codes ascend: cc outer, jj inner)
    #pragma unroll
    for (int jj = 0; jj < 2; ++jj) {
      const int code = cc*256 + w*32 + jj*16 + cl;
      #pragma unroll
      for (int i = 0; i < 4; ++i)
        #pragma unroll
        for (int r = 0; r < 4; ++r) {
          const float sc = e2v[jj] - 2.0f * acc[i][jj][r];
          if (sc < bestv[i][r]) { bestv[i][r] = sc; besti[i][r] = code; }
        }
    }
  }

  // ---- final argmin reduce: 16 code-lanes, then 8 waves via LDS ----
  struct RP { float v; int i; };
  RP*  red    = (RP*)(smem + 65536);          // [64][8]
  int* sh_idx = (int*)(smem + 65536 + 4096);  // [64]
  #pragma unroll
  for (int i = 0; i < 4; ++i)
    #pragma unroll
    for (int r = 0; r < 4; ++r) {
      float v = bestv[i][r]; int bi = besti[i][r];
      #pragma unroll
      for (int m = 1; m < 16; m <<= 1) {
        const float ov = __shfl_xor(v, m, 64);
        const int   oi = __shfl_xor(bi, m, 64);
        if (ov < v || (ov == v && oi < bi)) { v = ov; bi = oi; }
      }
      if (cl == 0) {                 // lanes 0,16,32,48 own token i*16+g*4+r
        const int tl = i*16 + g*4 + r;
        red[tl*8 + w].v = v; red[tl*8 + w].i = bi;
      }
    }
  __syncthreads();
  if (tid < 64) {
    float v = red[tid*8].v; int bi = red[tid*8].i;
    #pragma unroll
    for (int x = 1; x < 8; ++x) {
      const float ov = red[tid*8 + x].v; const int oi = red[tid*8 + x].i;
      if (ov < v || (ov == v && oi < bi)) { v = ov; bi = oi; }
    }
    zidx_f[t0 + tid] = (float)bi;
    sh_idx[tid] = bi;
  }
  __syncthreads();

  // ---- fused gather: quant[t] = e[idx[t]] (f32, e is L2-resident) ----
  {
    const int r   = tid >> 3;              // token row 0..63
    const int cq  = (tid & 7) << 5;        // col base 0..224
    const int idx = sh_idx[r];
    #pragma unroll
    for (int it = 0; it < 4; ++it) {
      const float4 v0 = *(const float4*)&eg[(size_t)idx * CDIM + cq + it*8];
      const float4 v1 = *(const float4*)&eg[(size_t)idx * CDIM + cq + it*8 + 4];
      *(float4*)&quant[(size_t)(t0 + r) * CDIM + cq + it*8]     = v0;
      *(float4*)&quant[(size_t)(t0 + r) * CDIM + cq + it*8 + 4] = v1;
    }
  }
}

// ---------------- launch ----------------------------------------------------
extern "C" void kernel_launch(void* const* d_in, const int* in_sizes, int n_in,
                              void* d_out, int out_size, void* d_ws, size_t ws_size,
                              hipStream_t stream) {
  const float* encode = (const float*)d_in[0];
  const float* cb     = (const float*)d_in[1];
  const float* pw     = (const float*)d_in[2];
  const float* pb     = (const float*)d_in[3];

  float* e  = (float*)d_ws;                           // 4 MB
  float* e2 = e + (size_t)K_CODES * CDIM;             // 16 KB
  unsigned short* Ect = (unsigned short*)(e2 + K_CODES); // 4 MB fragment-linear

  float* out     = (float*)d_out;
  float* zidx_f  = out;
  float* quant_f = out + NTOK;

  (void)hipFuncSetAttribute((const void*)score_mfma,
                            hipFuncAttributeMaxDynamicSharedMemorySize, 70912);

  proj_gemm<<<dim3(CDIM/64, K_CODES/64), 256, 0, stream>>>(cb, pw, pb, e, Ect);
  compute_e2<<<(K_CODES*64)/256, 256, 0, stream>>>(e, e2);
  score_mfma<<<NTOK/64, 512, 70912, stream>>>(encode, Ect, e2, e, zidx_f, quant_f);
}

// Round 13
// 252.907 us; speedup vs baseline: 1.0972x; 1.0155x over previous
//
#include <hip/hip_runtime.h>
#include <hip/hip_bf16.h>

// QuantiZ: e = codebook[4096,1024] @ proj_w[256,1024]^T + proj_b
//          zidx[t] = argmin_k ||z_t - e_k||, quant[t] = e[zidx[t]]
// d_out FLOAT32: [ zidx as float (32768) | quant (32768*256) ].
// Score GEMM: split-bf16 3-term (hi*hi + hi*lo + lo*hi), 16x16x32 MFMA.
// R13: wave code-tile 32->64 (jj in 4): 48 MFMA per 8 ds_read -> LDS pipe
//      drops from co-critical (83% of MFMA) to 41%. cc = 8 x 512 codes.

#define K_CODES 4096
#define CDIM    256
#define IDIM    1024
#define NTOK    32768

typedef __attribute__((ext_vector_type(8))) short short8;
typedef __attribute__((ext_vector_type(4))) float f32x4;

__device__ __forceinline__ unsigned short f32_to_bf16_rne(float f) {
  union { float f; unsigned int u; } x; x.f = f;
  unsigned int r = x.u + 0x7FFFu + ((x.u >> 16) & 1u);
  return (unsigned short)(r >> 16);
}
__device__ __forceinline__ float bf16_to_f32(unsigned short h) {
  union { unsigned int u; float f; } x; x.u = ((unsigned int)h) << 16;
  return x.f;
}

// ---- Kernel A: e = cb @ pw^T + pb (f32 64x64 tile) + fused Ect split -------
// Ect layout: frag(kb 0..15, ct 0..255) = 1024 B at (kb*256+ct)*1024,
// lane lf = g*16 + cl holds k-octet g of code ct*16+cl; kb0-7 hi, 8-15 lo.
extern "C" __global__ __launch_bounds__(256)
void proj_gemm(const float* __restrict__ cb, const float* __restrict__ pw,
               const float* __restrict__ pb, float* __restrict__ e,
               unsigned short* __restrict__ Ect) {
  __shared__ float As[64][33];
  __shared__ float Bs[64][33];
  const int tid = threadIdx.x;
  const int tx = tid & 15, ty = tid >> 4;
  const int m0 = blockIdx.y << 6;
  const int n0 = blockIdx.x << 6;
  const int r  = tid >> 2;
  const int c8 = (tid & 3) << 3;
  float acc[4][4] = {};
  for (int k0 = 0; k0 < IDIM; k0 += 32) {
    float4 a0 = *(const float4*)&cb[(m0 + r) * IDIM + k0 + c8];
    float4 a1 = *(const float4*)&cb[(m0 + r) * IDIM + k0 + c8 + 4];
    float4 b0 = *(const float4*)&pw[(n0 + r) * IDIM + k0 + c8];
    float4 b1 = *(const float4*)&pw[(n0 + r) * IDIM + k0 + c8 + 4];
    __syncthreads();
    As[r][c8+0]=a0.x; As[r][c8+1]=a0.y; As[r][c8+2]=a0.z; As[r][c8+3]=a0.w;
    As[r][c8+4]=a1.x; As[r][c8+5]=a1.y; As[r][c8+6]=a1.z; As[r][c8+7]=a1.w;
    Bs[r][c8+0]=b0.x; Bs[r][c8+1]=b0.y; Bs[r][c8+2]=b0.z; Bs[r][c8+3]=b0.w;
    Bs[r][c8+4]=b1.x; Bs[r][c8+5]=b1.y; Bs[r][c8+6]=b1.z; Bs[r][c8+7]=b1.w;
    __syncthreads();
    #pragma unroll
    for (int kk = 0; kk < 32; ++kk) {
      float av[4], bv[4];
      #pragma unroll
      for (int i = 0; i < 4; ++i) av[i] = As[ty*4 + i][kk];
      #pragma unroll
      for (int j = 0; j < 4; ++j) bv[j] = Bs[tx*4 + j][kk];
      #pragma unroll
      for (int i = 0; i < 4; ++i)
        #pragma unroll
        for (int j = 0; j < 4; ++j)
          acc[i][j] += av[i] * bv[j];
    }
  }
  // epilogue: write e (f32) and fragment-linear hi/lo bf16 Ect
  const int col0 = n0 + tx*4;
  const int kb   = col0 >> 5;
  const int g    = (col0 >> 3) & 3;
  const int half = (col0 >> 2) & 1;
  #pragma unroll
  for (int i = 0; i < 4; ++i) {
    const int row = m0 + ty*4 + i;
    float vv[4];
    unsigned short h4[4], l4[4];
    #pragma unroll
    for (int j = 0; j < 4; ++j) {
      vv[j] = acc[i][j] + pb[col0 + j];
      h4[j] = f32_to_bf16_rne(vv[j]);
      l4[j] = f32_to_bf16_rne(vv[j] - bf16_to_f32(h4[j]));
    }
    *(float4*)&e[(size_t)row * CDIM + col0] = *(float4*)vv;
    const int ct = row >> 4, cl = row & 15;
    const size_t fi = ((size_t)(kb      * 256 + ct) * 64 + g*16 + cl) * 8 + half*4;
    const size_t fo = ((size_t)((kb+8)  * 256 + ct) * 64 + g*16 + cl) * 8 + half*4;
    *(ushort4*)&Ect[fi] = *(ushort4*)h4;
    *(ushort4*)&Ect[fo] = *(ushort4*)l4;
  }
}

// ---------------- Kernel A3: e2[k] = sum_c e[k][c]^2 ------------------------
extern "C" __global__ __launch_bounds__(256)
void compute_e2(const float* __restrict__ e, float* __restrict__ e2) {
  const int gid  = blockIdx.x * 256 + threadIdx.x;
  const int w    = gid >> 6;
  const int lane = threadIdx.x & 63;
  float4 v = *(const float4*)&e[(size_t)w * CDIM + (lane << 2)];
  float s = v.x*v.x + v.y*v.y + v.z*v.z + v.w*v.w;
  #pragma unroll
  for (int off = 32; off > 0; off >>= 1) s += __shfl_down(s, off, 64);
  if (lane == 0) e2[w] = s;
}

// ---------------- Kernel B: MFMA score + argmin + fused gather --------------
// 64 tokens/block, 8 waves; wave = 64 tok x 64 codes (i in 4, jj in 4).
// LDS: Z as 64 fragment-linear frags (zero-conflict lane-order ds_read).
// 3-term split: hi*hi + hi*lo + lo*hi (48 MFMA per kw, 8 ds_read).
extern "C" __global__ __launch_bounds__(512, 2)
void score_mfma(const float* __restrict__ z, const unsigned short* __restrict__ Ect,
                const float* __restrict__ e2g, const float* __restrict__ eg,
                float* __restrict__ zidx_f, float* __restrict__ quant) {
  extern __shared__ __align__(16) char smem[];   // 64K Z + 4K red + 256 idx
  char* Zb = smem;

  const int tid = threadIdx.x;
  const int l   = tid & 63;
  const int w   = tid >> 6;          // wave 0..7: code slice w*64 within each cc
  const int t0  = blockIdx.x << 6;   // 64 tokens per block

  // ---- stage Z (hi/lo bf16) into fragment-linear LDS frags ----
  {
    const int r  = tid >> 3;              // token row 0..63
    const int cq = tid & 7;               // col base cq*32
    const int i4 = r >> 4;                // frag i
    const int rl = (r & 15) << 4;         // lane-slot byte within frag
    #pragma unroll
    for (int it = 0; it < 4; ++it) {
      const int col = cq*32 + it*8;       // g = it, kb_hi = cq, kb_lo = cq+8
      const float4 v0 = *(const float4*)&z[(size_t)(t0 + r) * CDIM + col];
      const float4 v1 = *(const float4*)&z[(size_t)(t0 + r) * CDIM + col + 4];
      float vv[8] = {v0.x,v0.y,v0.z,v0.w,v1.x,v1.y,v1.z,v1.w};
      unsigned int hp[4], lp[4];
      #pragma unroll
      for (int c = 0; c < 4; ++c) {
        unsigned short h0 = f32_to_bf16_rne(vv[2*c]);
        unsigned short h1 = f32_to_bf16_rne(vv[2*c+1]);
        unsigned short l0 = f32_to_bf16_rne(vv[2*c]   - bf16_to_f32(h0));
        unsigned short l1 = f32_to_bf16_rne(vv[2*c+1] - bf16_to_f32(h1));
        hp[c] = (unsigned int)h0 | ((unsigned int)h1 << 16);
        lp[c] = (unsigned int)l0 | ((unsigned int)l1 << 16);
      }
      const int lane_b = it*256 + rl;     // (g*16 + (r&15)) * 16
      *(uint4*)(Zb + (size_t)(i4*16 + cq    ) * 1024 + lane_b) = *(uint4*)hp;
      *(uint4*)(Zb + (size_t)(i4*16 + cq + 8) * 1024 + lane_b) = *(uint4*)lp;
    }
  }
  __syncthreads();   // Z ready; no further barriers until final reduce

  float bestv[4][4];
  int   besti[4][4];
  #pragma unroll
  for (int i = 0; i < 4; ++i)
    #pragma unroll
    for (int r = 0; r < 4; ++r) { bestv[i][r] = 3.4e38f; besti[i][r] = 0; }

  const int cl = l & 15;
  const int g  = l >> 4;

  // per-lane E base: frag(kb, ct) byte offset = kb*262144 + ct*1024 + l*16
  // wave w owns tiles ct = cc*32 + w*4 + jj
  const char* ebase = (const char*)Ect + (size_t)l * 16 + (size_t)w * 4096;
  const char* Zl    = Zb + (size_t)l * 16;

  for (int cc = 0; cc < 8; ++cc) {               // 512-code chunks
    const char* ecc = ebase + (size_t)cc * 32768;

    f32x4 acc[4][4];
    #pragma unroll
    for (int i = 0; i < 4; ++i)
      #pragma unroll
      for (int jj = 0; jj < 4; ++jj) acc[i][jj] = (f32x4){0.f,0.f,0.f,0.f};

    float e2v[4];
    #pragma unroll
    for (int jj = 0; jj < 4; ++jj)
      e2v[jj] = e2g[cc*512 + w*64 + jj*16 + cl];

    #pragma unroll
    for (int kw = 0; kw < 8; ++kw) {
      short8 aH[4], aL[4], bH[4], bL[4];
      #pragma unroll
      for (int jj = 0; jj < 4; ++jj) {
        bH[jj] = *(const short8*)(ecc + (size_t)(kw    ) * 262144 + jj * 1024);
        bL[jj] = *(const short8*)(ecc + (size_t)(kw + 8) * 262144 + jj * 1024);
      }
      #pragma unroll
      for (int i = 0; i < 4; ++i) {
        aH[i] = *(const short8*)(Zl + (size_t)(i*16 + kw    ) * 1024);
        aL[i] = *(const short8*)(Zl + (size_t)(i*16 + kw + 8) * 1024);
      }
      __builtin_amdgcn_s_setprio(1);
      #pragma unroll
      for (int i = 0; i < 4; ++i)
        #pragma unroll
        for (int jj = 0; jj < 4; ++jj)
          acc[i][jj] = __builtin_amdgcn_mfma_f32_16x16x32_bf16(aH[i], bH[jj], acc[i][jj], 0, 0, 0);
      #pragma unroll
      for (int i = 0; i < 4; ++i)
        #pragma unroll
        for (int jj = 0; jj < 4; ++jj)
          acc[i][jj] = __builtin_amdgcn_mfma_f32_16x16x32_bf16(aH[i], bL[jj], acc[i][jj], 0, 0, 0);
      #pragma unroll
      for (int i = 0; i < 4; ++i)
        #pragma unroll
        for (int jj = 0; jj < 4; ++jj)
          acc[i][jj] = __builtin_amdgcn_mfma_f32_16x16x32_bf16(aL[i], bH[jj], acc[i][jj], 0, 0, 0);
      __builtin_amdgcn_s_setprio(0);
    }
    // epilogue: scores -> running argmin (codes ascend: cc outer, jj inner)
    #pragma unroll
    for (int jj = 0; jj < 4; ++jj) {
      const int code = cc*512 + w*64 + jj*16 + cl;
      #pragma unroll
      for (int i = 0; i < 4; ++i)
        #pragma unroll
        for (int r = 0; r < 4; ++r) {
          const float sc = e2v[jj] - 2.0f * acc[i][jj][r];
          if (sc < bestv[i][r]) { bestv[i][r] = sc; besti[i][r] = code; }
        }
    }
  }

  // ---- final argmin reduce: 16 code-lanes, then 8 waves via LDS ----
  struct RP { float v; int i; };
  RP*  red    = (RP*)(smem + 65536);          // [64][8]
  int* sh_idx = (int*)(smem + 65536 + 4096);  // [64]
  #pragma unroll
  for (int i = 0; i < 4; ++i)
    #pragma unroll
    for (int r = 0; r < 4; ++r) {
      float v = bestv[i][r]; int bi = besti[i][r];
      #pragma unroll
      for (int m = 1; m < 16; m <<= 1) {
        const float ov = __shfl_xor(v, m, 64);
        const int   oi = __shfl_xor(bi, m, 64);
        if (ov < v || (ov == v && oi < bi)) { v = ov; bi = oi; }
      }
      if (cl == 0) {                 // lanes 0,16,32,48 own token i*16+g*4+r
        const int tl = i*16 + g*4 + r;
        red[tl*8 + w].v = v; red[tl*8 + w].i = bi;
      }
    }
  __syncthreads();
  if (tid < 64) {
    float v = red[tid*8].v; int bi = red[tid*8].i;
    #pragma unroll
    for (int x = 1; x < 8; ++x) {
      const float ov = red[tid*8 + x].v; const int oi = red[tid*8 + x].i;
      if (ov < v || (ov == v && oi < bi)) { v = ov; bi = oi; }
    }
    zidx_f[t0 + tid] = (float)bi;
    sh_idx[tid] = bi;
  }
  __syncthreads();

  // ---- fused gather: quant[t] = e[idx[t]] (f32, e is L2-resident) ----
  {
    const int r   = tid >> 3;              // token row 0..63
    const int cq  = (tid & 7) << 5;        // col base 0..224
    const int idx = sh_idx[r];
    #pragma unroll
    for (int it = 0; it < 4; ++it) {
      const float4 v0 = *(const float4*)&eg[(size_t)idx * CDIM + cq + it*8];
      const float4 v1 = *(const float4*)&eg[(size_t)idx * CDIM + cq + it*8 + 4];
      *(float4*)&quant[(size_t)(t0 + r) * CDIM + cq + it*8]     = v0;
      *(float4*)&quant[(size_t)(t0 + r) * CDIM + cq + it*8 + 4] = v1;
    }
  }
}

// ---------------- launch ----------------------------------------------------
extern "C" void kernel_launch(void* const* d_in, const int* in_sizes, int n_in,
                              void* d_out, int out_size, void* d_ws, size_t ws_size,
                              hipStream_t stream) {
  const float* encode = (const float*)d_in[0];
  const float* cb     = (const float*)d_in[1];
  const float* pw     = (const float*)d_in[2];
  const float* pb     = (const float*)d_in[3];

  float* e  = (float*)d_ws;                           // 4 MB
  float* e2 = e + (size_t)K_CODES * CDIM;             // 16 KB
  unsigned short* Ect = (unsigned short*)(e2 + K_CODES); // 4 MB fragment-linear

  float* out     = (float*)d_out;
  float* zidx_f  = out;
  float* quant_f = out + NTOK;

  (void)hipFuncSetAttribute((const void*)score_mfma,
                            hipFuncAttributeMaxDynamicSharedMemorySize, 70912);

  proj_gemm<<<dim3(CDIM/64, K_CODES/64), 256, 0, stream>>>(cb, pw, pb, e, Ect);
  compute_e2<<<(K_CODES*64)/256, 256, 0, stream>>>(e, e2);
  score_mfma<<<NTOK/64, 512, 70912, stream>>>(encode, Ect, e2, e, zidx_f, quant_f);
}